// Round 1
// baseline (4007.529 us; speedup 1.0000x reference)
//
#include <hip/hip_runtime.h>
#include <cstdint>
#include <cstddef>

#define T_LEN 1024
#define CH    1024
#define NGATE 4096
#define LAT   128
#define NBLK  128   // cooperative LSTM blocks; each owns 8 hidden dims

// ---------------- ws layout (bytes) ----------------
// [0, 16 MiB)   : xg[T][4096]        precomputed input gates (+biases)
// [+0 KiB]      : hbuf64[2][1024]    tagged h broadcast (u64: tag<<32 | bits)
// [+16 KiB]     : hfin64[1024]       tagged final h (tag==1)
// [+24 KiB]     : cfin64[1024]       tagged final c (tag==1)
// [+32 KiB]     : ctrl[1] : {eos_idx}
#define WS_XG    0
#define WS_HBUF  (16777216)
#define WS_HFIN  (16777216 + 16384)
#define WS_CFIN  (16777216 + 24576)
#define WS_CTRL  (16777216 + 32768)

// LDS swizzle: spread 64B-strided ds_read_b128 across all 8 16B bank slots.
#define SWZ(i) ((i) ^ ((((i) >> 4) & 7) << 2))

__device__ __forceinline__ float sigmf(float x) { return 1.0f / (1.0f + expf(-x)); }

template <int CTRL, int RM>
__device__ __forceinline__ float dpp_add(float x) {
  int t = __builtin_amdgcn_update_dpp(0, __float_as_int(x), CTRL, RM, 0xf, true);
  return x + __int_as_float(t);
}

// 64-lane sum via DPP (VALU pipe only, no DS ops). Result valid in lane 63.
__device__ __forceinline__ float wave_sum63(float x) {
  x = dpp_add<0x111, 0xf>(x);   // row_shr:1
  x = dpp_add<0x112, 0xf>(x);   // row_shr:2
  x = dpp_add<0x114, 0xf>(x);   // row_shr:4
  x = dpp_add<0x118, 0xf>(x);   // row_shr:8  -> lane15 of each row = row sum
  x = dpp_add<0x142, 0xa>(x);   // row_bcast:15 -> rows 1,3
  x = dpp_add<0x143, 0xc>(x);   // row_bcast:31 -> rows 2,3; lane 63 = total
  return x;
}

// ---------------- kernel A: eos index ----------------
__global__ __launch_bounds__(1024) void setup_k(const int* __restrict__ tok,
                                                int* __restrict__ ctrl) {
  __shared__ int red[1024];
  int tid = threadIdx.x;
  red[tid] = (tok[tid] == 1) ? tid : 0x7fffffff;
  __syncthreads();
  for (int s = 512; s > 0; s >>= 1) {
    if (tid < s) red[tid] = min(red[tid], red[tid + s]);
    __syncthreads();
  }
  if (tid == 0) {
    int e = red[0];
    ctrl[0] = (e == 0x7fffffff) ? 0 : e;   // argmax of all-false is 0
  }
}

// ---------------- kernel B: xg = gather(emb) @ W_ih^T + b_ih + b_hh ----------------
// C[t][r], tiles 128(t) x 128(r), 512 threads, 4x8 microtile, K-chunk 16.
__global__ __launch_bounds__(512) void xgemm_k(const int* __restrict__ tok,
                                               const float* __restrict__ emb,
                                               const float* __restrict__ Wih,
                                               const float* __restrict__ bih,
                                               const float* __restrict__ bhh,
                                               float* __restrict__ xg) {
  __shared__ float As[16 * 132];   // As[k][m] transposed, pad 132
  __shared__ float Bs[16 * 132];   // Bs[k][n]
  const int tid = threadIdx.x;
  const int r0 = blockIdx.x * 128;
  const int t0 = blockIdx.y * 128;
  const int tx = tid & 15, ty = tid >> 4;     // tx: r micro (8), ty: t micro (4)
  const int m0 = ty * 4, n0 = tx * 8;
  const int lrow = tid >> 2;                  // 0..127 loader row
  const int kq   = (tid & 3) * 4;             // 0,4,8,12

  float acc[4][8];
#pragma unroll
  for (int i = 0; i < 4; i++)
#pragma unroll
    for (int j = 0; j < 8; j++) acc[i][j] = 0.0f;

  const int tokv = tok[t0 + lrow];
  const float* arow = emb + (size_t)tokv * CH;
  const float* brow = Wih + (size_t)(r0 + lrow) * CH;

  for (int k0 = 0; k0 < CH; k0 += 16) {
    float4 a4 = *(const float4*)(arow + k0 + kq);
    float4 b4 = *(const float4*)(brow + k0 + kq);
    __syncthreads();   // previous iter's LDS reads complete
    As[(kq + 0) * 132 + lrow] = a4.x;
    As[(kq + 1) * 132 + lrow] = a4.y;
    As[(kq + 2) * 132 + lrow] = a4.z;
    As[(kq + 3) * 132 + lrow] = a4.w;
    Bs[(kq + 0) * 132 + lrow] = b4.x;
    Bs[(kq + 1) * 132 + lrow] = b4.y;
    Bs[(kq + 2) * 132 + lrow] = b4.z;
    Bs[(kq + 3) * 132 + lrow] = b4.w;
    __syncthreads();
#pragma unroll
    for (int kk = 0; kk < 16; kk++) {
      float4 av = *(const float4*)&As[kk * 132 + m0];
      float4 b0 = *(const float4*)&Bs[kk * 132 + n0];
      float4 b1 = *(const float4*)&Bs[kk * 132 + n0 + 4];
      float aa[4] = {av.x, av.y, av.z, av.w};
      float bb[8] = {b0.x, b0.y, b0.z, b0.w, b1.x, b1.y, b1.z, b1.w};
#pragma unroll
      for (int i = 0; i < 4; i++)
#pragma unroll
        for (int j = 0; j < 8; j++) acc[i][j] += aa[i] * bb[j];
    }
  }

  float4 bi0 = *(const float4*)(bih + r0 + n0);
  float4 bi1 = *(const float4*)(bih + r0 + n0 + 4);
  float4 bh0 = *(const float4*)(bhh + r0 + n0);
  float4 bh1 = *(const float4*)(bhh + r0 + n0 + 4);
  float badd[8] = {bi0.x + bh0.x, bi0.y + bh0.y, bi0.z + bh0.z, bi0.w + bh0.w,
                   bi1.x + bh1.x, bi1.y + bh1.y, bi1.z + bh1.z, bi1.w + bh1.w};
#pragma unroll
  for (int i = 0; i < 4; i++) {
    float4 o0 = {acc[i][0] + badd[0], acc[i][1] + badd[1],
                 acc[i][2] + badd[2], acc[i][3] + badd[3]};
    float4 o1 = {acc[i][4] + badd[4], acc[i][5] + badd[5],
                 acc[i][6] + badd[6], acc[i][7] + badd[7]};
    float* dst = xg + (size_t)(t0 + m0 + i) * NGATE + r0 + n0;
    *(float4*)(dst) = o0;
    *(float4*)(dst + 4) = o1;
  }
}

// ---------------- kernel C: cooperative LSTM + projections ----------------
// 128 blocks x 1024 threads. Block b owns hidden dims [b*8, b*8+8).
//
// Restructured inner loop (vs prior version):
//  - Wave d (d<8) owns h-dim b*8+d: its 4 gate rows q*1024+b*8+d, q=0..3.
//    Lane ln covers k in [ln*16, ln*16+16); weights w4[4][4] in registers
//    (64 VGPR) -> 4 FMAs per LDS read, 4x ds_read_b128 per thread instead of
//    32x ds_read_b32 (DS-pipe instrs per CU per step: ~600 -> ~48).
//  - hs stored XOR-swizzled so the 64B-strided b128 reads hit all 8 bank
//    slots (native conflict-free b128 pattern).
//  - Gate reduction via DPP row_shr/row_bcast (VALU pipe, no ds_swizzle),
//    lands i,f,g,o in lane 63, which holds (h,c) state, applies exact
//    expf/tanhf gates, and publishes its dim independently.
//  - ONE __syncthreads per step; hs double-buffered (waves 8..15 are pure
//    pollers and may legally run one step ahead; D=2 tag protocol as before).
//
// Cross-block h exchange: fence-free tagged 64-bit relaxed device-scope atomics.
// Payload = (tag<<32)|float_bits; tag t+1 published into slot (t+1)&1.
// D=2 double-buffer is race-free: publishing tag t+2 requires having consumed
// ALL tags t+1, which implies every block finished reading slot t&1.
__global__ __launch_bounds__(1024) void lstm_k(const float* __restrict__ h0,
                                               const float* __restrict__ c0,
                                               const float* __restrict__ eps,
                                               const float* __restrict__ Whh,
                                               const float* __restrict__ Wm,
                                               const float* __restrict__ bm,
                                               const float* __restrict__ Wl,
                                               const float* __restrict__ bl,
                                               const float* __restrict__ xg,
                                               unsigned long long* __restrict__ hbuf64,
                                               unsigned long long* __restrict__ hfin64,
                                               unsigned long long* __restrict__ cfin64,
                                               const int* __restrict__ ctrl,
                                               float* __restrict__ out) {
  __shared__ float hs[2][1024];
  __shared__ float hcs[2048];
  __shared__ float rs[32];

  const int tid = threadIdx.x;
  const int b = blockIdx.x;
  const int wv = tid >> 6;   // wave 0..15
  const int ln = tid & 63;   // lane

  // weight fragments: wave d<8 owns h-dim b*8+d; lane covers 16 k-values
  float4 w4[4][4];
  if (wv < 8) {
#pragma unroll
    for (int q = 0; q < 4; q++) {
      const float* wr = Whh + (size_t)(q * 1024 + b * 8 + wv) * CH + ln * 16;
#pragma unroll
      for (int m = 0; m < 4; m++) w4[q][m] = *(const float4*)(wr + 4 * m);
    }
  }

  const int eos = ctrl[0];

  float hreg = 0.0f, creg = 0.0f;
  if (wv < 8 && ln == 63) { hreg = h0[b * 8 + wv]; creg = c0[b * 8 + wv]; }

  for (int t = 0; t < eos; t++) {
    // prefetch this step's input-gate values; hidden under the poll latency
    float xq0 = 0.0f, xq1 = 0.0f, xq2 = 0.0f, xq3 = 0.0f;
    if (wv < 8 && ln == 63) {
      const float* xp = xg + (size_t)t * NGATE + b * 8 + wv;
      xq0 = xp[0]; xq1 = xp[1024]; xq2 = xp[2048]; xq3 = xp[3072];
    }

    const int pb = t & 1;
    if (t == 0) {
      hs[0][SWZ(tid)] = h0[tid];
    } else {
      const unsigned want = (unsigned)t;
      const unsigned long long* src = hbuf64 + (size_t)pb * 1024 + tid;
      unsigned long long v;
      do {
        v = __hip_atomic_load(src, __ATOMIC_RELAXED, __HIP_MEMORY_SCOPE_AGENT);
      } while ((unsigned)(v >> 32) != want);
      hs[pb][SWZ(tid)] = __uint_as_float((unsigned)(v & 0xffffffffu));
    }
    __syncthreads();   // hs[pb] complete; only barrier in the step

    if (wv < 8) {
      const float* hb = hs[pb];
      float a0 = 0.0f, a1 = 0.0f, a2 = 0.0f, a3 = 0.0f;
#pragma unroll
      for (int m = 0; m < 4; m++) {
        const int idx = (ln * 16 + 4 * m) ^ ((ln & 7) << 2);
        const float4 h4 = *(const float4*)(hb + idx);
        a0 += w4[0][m].x * h4.x; a0 += w4[0][m].y * h4.y;
        a0 += w4[0][m].z * h4.z; a0 += w4[0][m].w * h4.w;
        a1 += w4[1][m].x * h4.x; a1 += w4[1][m].y * h4.y;
        a1 += w4[1][m].z * h4.z; a1 += w4[1][m].w * h4.w;
        a2 += w4[2][m].x * h4.x; a2 += w4[2][m].y * h4.y;
        a2 += w4[2][m].z * h4.z; a2 += w4[2][m].w * h4.w;
        a3 += w4[3][m].x * h4.x; a3 += w4[3][m].y * h4.y;
        a3 += w4[3][m].z * h4.z; a3 += w4[3][m].w * h4.w;
      }
      a0 = wave_sum63(a0);
      a1 = wave_sum63(a1);
      a2 = wave_sum63(a2);
      a3 = wave_sum63(a3);

      if (ln == 63) {
        const float iv = a0 + xq0, fv = a1 + xq1, gg = a2 + xq2, ov = a3 + xq3;
        const float cn = sigmf(fv) * creg + sigmf(iv) * tanhf(gg);
        const float hn = sigmf(ov) * tanhf(cn);
        creg = cn; hreg = hn;
        const unsigned long long pv =
            ((unsigned long long)(unsigned)(t + 1) << 32) |
            (unsigned long long)__float_as_uint(hn);
        __hip_atomic_store(&hbuf64[(size_t)((t + 1) & 1) * 1024 + b * 8 + wv], pv,
                           __ATOMIC_RELAXED, __HIP_MEMORY_SCOPE_AGENT);
      }
    }
  }

  // publish final h, c into dedicated tagged buffers (tag == 1; poison never matches)
  if (wv < 8 && ln == 63) {
    const unsigned long long ph = (1ull << 32) | (unsigned long long)__float_as_uint(hreg);
    const unsigned long long pc = (1ull << 32) | (unsigned long long)__float_as_uint(creg);
    __hip_atomic_store(&hfin64[b * 8 + wv], ph, __ATOMIC_RELAXED, __HIP_MEMORY_SCOPE_AGENT);
    __hip_atomic_store(&cfin64[b * 8 + wv], pc, __ATOMIC_RELAXED, __HIP_MEMORY_SCOPE_AGENT);
  }

  // gather full hc = concat(h, c)
  {
    unsigned long long vh, vc;
    do {
      vh = __hip_atomic_load(&hfin64[tid], __ATOMIC_RELAXED, __HIP_MEMORY_SCOPE_AGENT);
    } while ((unsigned)(vh >> 32) != 1u);
    do {
      vc = __hip_atomic_load(&cfin64[tid], __ATOMIC_RELAXED, __HIP_MEMORY_SCOPE_AGENT);
    } while ((unsigned)(vc >> 32) != 1u);
    hcs[tid] = __uint_as_float((unsigned)(vh & 0xffffffffu));
    hcs[1024 + tid] = __uint_as_float((unsigned)(vc & 0xffffffffu));
  }
  __syncthreads();

  // projections: block b computes mean[b], logv[b] (2048-dot each)
  float hc1 = hcs[tid];
  float hc2 = hcs[1024 + tid];
  float pm = Wm[(size_t)b * 2048 + tid] * hc1 + Wm[(size_t)b * 2048 + 1024 + tid] * hc2;
  float pl = Wl[(size_t)b * 2048 + tid] * hc1 + Wl[(size_t)b * 2048 + 1024 + tid] * hc2;
#pragma unroll
  for (int o = 32; o > 0; o >>= 1) {
    pm += __shfl_down(pm, o);
    pl += __shfl_down(pl, o);
  }
  if (ln == 0) { rs[wv] = pm; rs[16 + wv] = pl; }
  __syncthreads();
  if (tid == 0) {
    float m = 0.0f, l = 0.0f;
    for (int i = 0; i < 16; i++) { m += rs[i]; l += rs[16 + i]; }
    m += bm[b];
    l += bl[b];
    float z = eps[b] * expf(0.5f * l) + m;
    out[b] = z;
    out[LAT + b] = m;
    out[2 * LAT + b] = l;
  }
}

extern "C" void kernel_launch(void* const* d_in, const int* in_sizes, int n_in,
                              void* d_out, int out_size, void* d_ws, size_t ws_size,
                              hipStream_t stream) {
  const int*   tok = (const int*)d_in[0];
  const float* h0  = (const float*)d_in[1];
  const float* c0  = (const float*)d_in[2];
  const float* eps = (const float*)d_in[3];
  const float* emb = (const float*)d_in[4];
  const float* Wih = (const float*)d_in[5];
  const float* Whh = (const float*)d_in[6];
  const float* bih = (const float*)d_in[7];
  const float* bhh = (const float*)d_in[8];
  const float* Wm  = (const float*)d_in[9];
  const float* bm  = (const float*)d_in[10];
  const float* Wl  = (const float*)d_in[11];
  const float* bl  = (const float*)d_in[12];
  float* out = (float*)d_out;

  char* ws = (char*)d_ws;
  float* xg = (float*)(ws + WS_XG);
  unsigned long long* hbuf64 = (unsigned long long*)(ws + WS_HBUF);
  unsigned long long* hfin64 = (unsigned long long*)(ws + WS_HFIN);
  unsigned long long* cfin64 = (unsigned long long*)(ws + WS_CFIN);
  int* ctrl = (int*)(ws + WS_CTRL);

  setup_k<<<1, 1024, 0, stream>>>(tok, ctrl);
  xgemm_k<<<dim3(NGATE / 128, T_LEN / 128), 512, 0, stream>>>(tok, emb, Wih, bih, bhh, xg);

  void* args[] = {(void*)&h0, (void*)&c0, (void*)&eps, (void*)&Whh,
                  (void*)&Wm, (void*)&bm, (void*)&Wl, (void*)&bl,
                  (void*)&xg, (void*)&hbuf64, (void*)&hfin64, (void*)&cfin64,
                  (void*)&ctrl, (void*)&out};
  hipLaunchCooperativeKernel((void*)lstm_k, dim3(NBLK), dim3(1024), args, 0, stream);
}

// Round 2
// 2493.603 us; speedup vs baseline: 1.6071x; 1.6071x over previous
//
#include <hip/hip_runtime.h>
#include <cstdint>
#include <cstddef>

#define T_LEN 1024
#define CH    1024
#define NGATE 4096
#define LAT   128
#define NBLK  128   // cooperative LSTM blocks; each owns 8 hidden dims

// ---------------- ws layout (bytes) ----------------
// [0, 16 MiB)   : xg[T][4096]        precomputed input gates (+biases)
// [+0 KiB]      : hbuf64[2][1024]    tagged h broadcast (u64: tag<<32 | bits)
// [+16 KiB]     : hfin64[1024]       tagged final h (tag==1)
// [+24 KiB]     : cfin64[1024]       tagged final c (tag==1)
// [+32 KiB]     : ctrl[1] : {eos_idx}
#define WS_XG    0
#define WS_HBUF  (16777216)
#define WS_HFIN  (16777216 + 16384)
#define WS_CFIN  (16777216 + 24576)
#define WS_CTRL  (16777216 + 32768)

// LDS swizzle for conflict-free ds_read_b128 at 64B lane stride:
// logical float index j stored at j ^ (((j>>4)&7)<<2).  For j in lane ln's
// 16-float chunk, (j>>4)&7 == ln&7, so reads use idx ^ ((ln&7)<<2) and the
// 8-lane phase groups hit 8 distinct 16B bank slots (verified: lanes 0..7 ->
// slots {0,20,8,28,16,4,24,12}a). Bits 0-1 untouched -> float4 stays contiguous.
#define SWZ(i) ((i) ^ ((((i) >> 4) & 7) << 2))

__device__ __forceinline__ float sigmf(float x) { return 1.0f / (1.0f + expf(-x)); }

template <int CTRL, int RM>
__device__ __forceinline__ float dpp_add(float x) {
  int t = __builtin_amdgcn_update_dpp(0, __float_as_int(x), CTRL, RM, 0xf, true);
  return x + __int_as_float(t);
}

// 64-lane sum via DPP (VALU pipe only, no DS ops). Result valid in lane 63.
__device__ __forceinline__ float wave_sum63(float x) {
  x = dpp_add<0x111, 0xf>(x);   // row_shr:1
  x = dpp_add<0x112, 0xf>(x);   // row_shr:2
  x = dpp_add<0x114, 0xf>(x);   // row_shr:4
  x = dpp_add<0x118, 0xf>(x);   // row_shr:8  -> lane15 of each row = row sum
  x = dpp_add<0x142, 0xa>(x);   // row_bcast:15 -> rows 1,3
  x = dpp_add<0x143, 0xc>(x);   // row_bcast:31 -> rows 2,3; lane 63 = total
  return x;
}

// ---------------- kernel A: eos index ----------------
__global__ __launch_bounds__(1024) void setup_k(const int* __restrict__ tok,
                                                int* __restrict__ ctrl) {
  __shared__ int red[1024];
  int tid = threadIdx.x;
  red[tid] = (tok[tid] == 1) ? tid : 0x7fffffff;
  __syncthreads();
  for (int s = 512; s > 0; s >>= 1) {
    if (tid < s) red[tid] = min(red[tid], red[tid + s]);
    __syncthreads();
  }
  if (tid == 0) {
    int e = red[0];
    ctrl[0] = (e == 0x7fffffff) ? 0 : e;   // argmax of all-false is 0
  }
}

// ---------------- kernel B: xg = gather(emb) @ W_ih^T + b_ih + b_hh ----------------
// C[t][r], tiles 128(t) x 128(r), 512 threads, 4x8 microtile, K-chunk 16.
__global__ __launch_bounds__(512) void xgemm_k(const int* __restrict__ tok,
                                               const float* __restrict__ emb,
                                               const float* __restrict__ Wih,
                                               const float* __restrict__ bih,
                                               const float* __restrict__ bhh,
                                               float* __restrict__ xg) {
  __shared__ float As[16 * 132];   // As[k][m] transposed, pad 132
  __shared__ float Bs[16 * 132];   // Bs[k][n]
  const int tid = threadIdx.x;
  const int r0 = blockIdx.x * 128;
  const int t0 = blockIdx.y * 128;
  const int tx = tid & 15, ty = tid >> 4;     // tx: r micro (8), ty: t micro (4)
  const int m0 = ty * 4, n0 = tx * 8;
  const int lrow = tid >> 2;                  // 0..127 loader row
  const int kq   = (tid & 3) * 4;             // 0,4,8,12

  float acc[4][8];
#pragma unroll
  for (int i = 0; i < 4; i++)
#pragma unroll
    for (int j = 0; j < 8; j++) acc[i][j] = 0.0f;

  const int tokv = tok[t0 + lrow];
  const float* arow = emb + (size_t)tokv * CH;
  const float* brow = Wih + (size_t)(r0 + lrow) * CH;

  for (int k0 = 0; k0 < CH; k0 += 16) {
    float4 a4 = *(const float4*)(arow + k0 + kq);
    float4 b4 = *(const float4*)(brow + k0 + kq);
    __syncthreads();   // previous iter's LDS reads complete
    As[(kq + 0) * 132 + lrow] = a4.x;
    As[(kq + 1) * 132 + lrow] = a4.y;
    As[(kq + 2) * 132 + lrow] = a4.z;
    As[(kq + 3) * 132 + lrow] = a4.w;
    Bs[(kq + 0) * 132 + lrow] = b4.x;
    Bs[(kq + 1) * 132 + lrow] = b4.y;
    Bs[(kq + 2) * 132 + lrow] = b4.z;
    Bs[(kq + 3) * 132 + lrow] = b4.w;
    __syncthreads();
#pragma unroll
    for (int kk = 0; kk < 16; kk++) {
      float4 av = *(const float4*)&As[kk * 132 + m0];
      float4 b0 = *(const float4*)&Bs[kk * 132 + n0];
      float4 b1 = *(const float4*)&Bs[kk * 132 + n0 + 4];
      float aa[4] = {av.x, av.y, av.z, av.w};
      float bb[8] = {b0.x, b0.y, b0.z, b0.w, b1.x, b1.y, b1.z, b1.w};
#pragma unroll
      for (int i = 0; i < 4; i++)
#pragma unroll
        for (int j = 0; j < 8; j++) acc[i][j] += aa[i] * bb[j];
    }
  }

  float4 bi0 = *(const float4*)(bih + r0 + n0);
  float4 bi1 = *(const float4*)(bih + r0 + n0 + 4);
  float4 bh0 = *(const float4*)(bhh + r0 + n0);
  float4 bh1 = *(const float4*)(bhh + r0 + n0 + 4);
  float badd[8] = {bi0.x + bh0.x, bi0.y + bh0.y, bi0.z + bh0.z, bi0.w + bh0.w,
                   bi1.x + bh1.x, bi1.y + bh1.y, bi1.z + bh1.z, bi1.w + bh1.w};
#pragma unroll
  for (int i = 0; i < 4; i++) {
    float4 o0 = {acc[i][0] + badd[0], acc[i][1] + badd[1],
                 acc[i][2] + badd[2], acc[i][3] + badd[3]};
    float4 o1 = {acc[i][4] + badd[4], acc[i][5] + badd[5],
                 acc[i][6] + badd[6], acc[i][7] + badd[7]};
    float* dst = xg + (size_t)(t0 + m0 + i) * NGATE + r0 + n0;
    *(float4*)(dst) = o0;
    *(float4*)(dst + 4) = o1;
  }
}

// ---------------- kernel C: cooperative LSTM + projections ----------------
// 128 blocks x 1024 threads. Block b owns hidden dims [b*8, b*8+8).
//
// Matvec restructure vs the 2460us baseline (ONLY change; roles for poll /
// gates / publish / state are the baseline's verbatim):
//  - Wave wv serves dim b*8+(wv&7); waves wv and wv+8 split the dot by
//    m-slice: wv<8 covers float4 slots m={0,1} of each lane's 16-float
//    k-chunk, wv>=8 covers m={2,3}.  Weights w4[4][2] = 32 floats/thread
//    (same register budget as baseline's w[32] -> no spill).
//  - Each h value now read 16x per block instead of 32x: LDS read volume
//    halves (32 ds_read_b128 vs 512 ds_read_b32 wave-instrs per step).
//  - hs XOR-swizzled (SWZ) so the 64B-stride b128 reads are bank-conflict-free.
//  - Reduction via DPP (VALU pipe) instead of ds_swizzle shuffles; lane 63
//    writes the wave's 4 gate partials to gpart[wv] (one b128 write).
//  - tid<8 combines gpart[tid]+gpart[tid+8]+xq, applies gates, publishes with
//    the baseline's single coalesced wave store.
//
// Cross-block h exchange: fence-free tagged 64-bit relaxed device-scope atomics.
// Payload = (tag<<32)|float_bits; tag t+1 published into slot (t+1)&1.
// D=2 double-buffer is race-free: publishing tag t+2 requires having consumed
// ALL tags t+1, which implies every block finished reading slot t&1.
__global__ __launch_bounds__(1024) void lstm_k(const float* __restrict__ h0,
                                               const float* __restrict__ c0,
                                               const float* __restrict__ eps,
                                               const float* __restrict__ Whh,
                                               const float* __restrict__ Wm,
                                               const float* __restrict__ bm,
                                               const float* __restrict__ Wl,
                                               const float* __restrict__ bl,
                                               const float* __restrict__ xg,
                                               unsigned long long* __restrict__ hbuf64,
                                               unsigned long long* __restrict__ hfin64,
                                               unsigned long long* __restrict__ cfin64,
                                               const int* __restrict__ ctrl,
                                               float* __restrict__ out) {
  __shared__ float hs[1024];
  __shared__ float hcs[2048];
  __shared__ float4 gpart[16];
  __shared__ float rs[32];

  const int tid = threadIdx.x;
  const int b = blockIdx.x;
  const int wv = tid >> 6;   // wave 0..15
  const int ln = tid & 63;   // lane
  const int dw = wv & 7;     // dim (within block) this wave serves
  const int mb = (wv >> 3) * 2;          // float4 slots {mb, mb+1}
  const int hsw = SWZ(tid);              // swizzled hs slot for this thread
  const int swzmask = (ln & 7) << 2;
  const int idx0 = (ln * 16 + 4 * mb) ^ swzmask;
  const int idx1 = (ln * 16 + 4 * mb + 4) ^ swzmask;

  // weight fragments: rows q*1024 + b*8 + dw, k = ln*16 + 4*{mb,mb+1}
  float4 w4[4][2];
#pragma unroll
  for (int q = 0; q < 4; q++) {
    const float* wr = Whh + (size_t)(q * 1024 + b * 8 + dw) * CH + ln * 16 + 4 * mb;
    w4[q][0] = *(const float4*)(wr);
    w4[q][1] = *(const float4*)(wr + 4);
  }

  const int eos = ctrl[0];

  float hreg = 0.0f, creg = 0.0f;
  if (tid < 8) { hreg = h0[b * 8 + tid]; creg = c0[b * 8 + tid]; }

  for (int t = 0; t < eos; t++) {
    // prefetch this step's input-gate values; hidden under the poll latency
    float xq0 = 0.0f, xq1 = 0.0f, xq2 = 0.0f, xq3 = 0.0f;
    if (tid < 8) {
      const float* xp = xg + (size_t)t * NGATE + b * 8 + tid;
      xq0 = xp[0]; xq1 = xp[1024]; xq2 = xp[2048]; xq3 = xp[3072];
    }

    if (t == 0) {
      hs[hsw] = h0[tid];
    } else {
      const unsigned want = (unsigned)t;
      const unsigned long long* src = hbuf64 + (size_t)(t & 1) * 1024 + tid;
      unsigned long long v;
      do {
        v = __hip_atomic_load(src, __ATOMIC_RELAXED, __HIP_MEMORY_SCOPE_AGENT);
      } while ((unsigned)(v >> 32) != want);
      hs[hsw] = __uint_as_float((unsigned)(v & 0xffffffffu));
    }
    __syncthreads();

    // partial matvec: this wave's m-slice of dim dw's four gate rows
    float a0 = 0.0f, a1 = 0.0f, a2 = 0.0f, a3 = 0.0f;
    {
      const float4 h4a = *(const float4*)&hs[idx0];
      const float4 h4b = *(const float4*)&hs[idx1];
      a0 += w4[0][0].x * h4a.x; a0 += w4[0][0].y * h4a.y;
      a0 += w4[0][0].z * h4a.z; a0 += w4[0][0].w * h4a.w;
      a0 += w4[0][1].x * h4b.x; a0 += w4[0][1].y * h4b.y;
      a0 += w4[0][1].z * h4b.z; a0 += w4[0][1].w * h4b.w;
      a1 += w4[1][0].x * h4a.x; a1 += w4[1][0].y * h4a.y;
      a1 += w4[1][0].z * h4a.z; a1 += w4[1][0].w * h4a.w;
      a1 += w4[1][1].x * h4b.x; a1 += w4[1][1].y * h4b.y;
      a1 += w4[1][1].z * h4b.z; a1 += w4[1][1].w * h4b.w;
      a2 += w4[2][0].x * h4a.x; a2 += w4[2][0].y * h4a.y;
      a2 += w4[2][0].z * h4a.z; a2 += w4[2][0].w * h4a.w;
      a2 += w4[2][1].x * h4b.x; a2 += w4[2][1].y * h4b.y;
      a2 += w4[2][1].z * h4b.z; a2 += w4[2][1].w * h4b.w;
      a3 += w4[3][0].x * h4a.x; a3 += w4[3][0].y * h4a.y;
      a3 += w4[3][0].z * h4a.z; a3 += w4[3][0].w * h4a.w;
      a3 += w4[3][1].x * h4b.x; a3 += w4[3][1].y * h4b.y;
      a3 += w4[3][1].z * h4b.z; a3 += w4[3][1].w * h4b.w;
    }
    a0 = wave_sum63(a0);
    a1 = wave_sum63(a1);
    a2 = wave_sum63(a2);
    a3 = wave_sum63(a3);
    if (ln == 63) gpart[wv] = float4{a0, a1, a2, a3};
    __syncthreads();   // gpart ready; also retires hs reads before next writes

    if (tid < 8) {
      const float4 g0 = gpart[tid];
      const float4 g1 = gpart[tid + 8];
      const float iv = g0.x + g1.x + xq0;
      const float fv = g0.y + g1.y + xq1;
      const float gg = g0.z + g1.z + xq2;
      const float ov = g0.w + g1.w + xq3;
      const float cn = sigmf(fv) * creg + sigmf(iv) * tanhf(gg);
      const float hn = sigmf(ov) * tanhf(cn);
      creg = cn; hreg = hn;
      const unsigned long long pv =
          ((unsigned long long)(unsigned)(t + 1) << 32) |
          (unsigned long long)__float_as_uint(hn);
      __hip_atomic_store(&hbuf64[(size_t)((t + 1) & 1) * 1024 + b * 8 + tid], pv,
                         __ATOMIC_RELAXED, __HIP_MEMORY_SCOPE_AGENT);
    }
  }

  // publish final h, c into dedicated tagged buffers (tag == 1; poison never matches)
  if (tid < 8) {
    const unsigned long long ph = (1ull << 32) | (unsigned long long)__float_as_uint(hreg);
    const unsigned long long pc = (1ull << 32) | (unsigned long long)__float_as_uint(creg);
    __hip_atomic_store(&hfin64[b * 8 + tid], ph, __ATOMIC_RELAXED, __HIP_MEMORY_SCOPE_AGENT);
    __hip_atomic_store(&cfin64[b * 8 + tid], pc, __ATOMIC_RELAXED, __HIP_MEMORY_SCOPE_AGENT);
  }

  // gather full hc = concat(h, c)
  {
    unsigned long long vh, vc;
    do {
      vh = __hip_atomic_load(&hfin64[tid], __ATOMIC_RELAXED, __HIP_MEMORY_SCOPE_AGENT);
    } while ((unsigned)(vh >> 32) != 1u);
    do {
      vc = __hip_atomic_load(&cfin64[tid], __ATOMIC_RELAXED, __HIP_MEMORY_SCOPE_AGENT);
    } while ((unsigned)(vc >> 32) != 1u);
    hcs[tid] = __uint_as_float((unsigned)(vh & 0xffffffffu));
    hcs[1024 + tid] = __uint_as_float((unsigned)(vc & 0xffffffffu));
  }
  __syncthreads();

  // projections: block b computes mean[b], logv[b] (2048-dot each)
  float hc1 = hcs[tid];
  float hc2 = hcs[1024 + tid];
  float pm = Wm[(size_t)b * 2048 + tid] * hc1 + Wm[(size_t)b * 2048 + 1024 + tid] * hc2;
  float pl = Wl[(size_t)b * 2048 + tid] * hc1 + Wl[(size_t)b * 2048 + 1024 + tid] * hc2;
#pragma unroll
  for (int o = 32; o > 0; o >>= 1) {
    pm += __shfl_down(pm, o);
    pl += __shfl_down(pl, o);
  }
  if (ln == 0) { rs[wv] = pm; rs[16 + wv] = pl; }
  __syncthreads();
  if (tid == 0) {
    float m = 0.0f, l = 0.0f;
    for (int i = 0; i < 16; i++) { m += rs[i]; l += rs[16 + i]; }
    m += bm[b];
    l += bl[b];
    float z = eps[b] * expf(0.5f * l) + m;
    out[b] = z;
    out[LAT + b] = m;
    out[2 * LAT + b] = l;
  }
}

extern "C" void kernel_launch(void* const* d_in, const int* in_sizes, int n_in,
                              void* d_out, int out_size, void* d_ws, size_t ws_size,
                              hipStream_t stream) {
  const int*   tok = (const int*)d_in[0];
  const float* h0  = (const float*)d_in[1];
  const float* c0  = (const float*)d_in[2];
  const float* eps = (const float*)d_in[3];
  const float* emb = (const float*)d_in[4];
  const float* Wih = (const float*)d_in[5];
  const float* Whh = (const float*)d_in[6];
  const float* bih = (const float*)d_in[7];
  const float* bhh = (const float*)d_in[8];
  const float* Wm  = (const float*)d_in[9];
  const float* bm  = (const float*)d_in[10];
  const float* Wl  = (const float*)d_in[11];
  const float* bl  = (const float*)d_in[12];
  float* out = (float*)d_out;

  char* ws = (char*)d_ws;
  float* xg = (float*)(ws + WS_XG);
  unsigned long long* hbuf64 = (unsigned long long*)(ws + WS_HBUF);
  unsigned long long* hfin64 = (unsigned long long*)(ws + WS_HFIN);
  unsigned long long* cfin64 = (unsigned long long*)(ws + WS_CFIN);
  int* ctrl = (int*)(ws + WS_CTRL);

  setup_k<<<1, 1024, 0, stream>>>(tok, ctrl);
  xgemm_k<<<dim3(NGATE / 128, T_LEN / 128), 512, 0, stream>>>(tok, emb, Wih, bih, bhh, xg);

  void* args[] = {(void*)&h0, (void*)&c0, (void*)&eps, (void*)&Whh,
                  (void*)&Wm, (void*)&bm, (void*)&Wl, (void*)&bl,
                  (void*)&xg, (void*)&hbuf64, (void*)&hfin64, (void*)&cfin64,
                  (void*)&ctrl, (void*)&out};
  hipLaunchCooperativeKernel((void*)lstm_k, dim3(NBLK), dim3(1024), args, 0, stream);
}